// Round 1
// baseline (109.227 us; speedup 1.0000x reference)
//
#include <hip/hip_runtime.h>

#define M_COLS 2048
#define KOUT 64
#define CAND 256
#define BLK 256

// One block per (n, q) row. Exact top-64 by |value| via radix-select on the
// 31-bit abs bit pattern, then bitonic sort of <=256 candidates, then
// wave-level softmax over the first k_n entries.
__global__ __launch_bounds__(BLK) void topk_route_kernel(
    const float* __restrict__ A, const int* __restrict__ topk,
    float* __restrict__ out_w, float* __restrict__ out_i) {
  __shared__ unsigned hist[4][256];          // per-wave histograms (atomic contention split)
  __shared__ unsigned sscan[256];            // suffix scan
  __shared__ unsigned long long cand[CAND];  // candidate keys
  __shared__ unsigned s_cnt, s_d, s_suf, s_sufn;

  const unsigned tid = threadIdx.x;
  const unsigned wv = tid >> 6;
  const unsigned row = blockIdx.x;
  const unsigned n = row >> 11;  // Q = 2048

  // Load 8 elements/thread, coalesced float4.
  const float4* a4 = (const float4*)(A + (size_t)row * M_COLS);
  float4 v0 = a4[tid];
  float4 v1 = a4[tid + BLK];

  unsigned bits[8];
  bits[0] = __float_as_uint(v0.x) & 0x7fffffffu;
  bits[1] = __float_as_uint(v0.y) & 0x7fffffffu;
  bits[2] = __float_as_uint(v0.z) & 0x7fffffffu;
  bits[3] = __float_as_uint(v0.w) & 0x7fffffffu;
  bits[4] = __float_as_uint(v1.x) & 0x7fffffffu;
  bits[5] = __float_as_uint(v1.y) & 0x7fffffffu;
  bits[6] = __float_as_uint(v1.z) & 0x7fffffffu;
  bits[7] = __float_as_uint(v1.w) & 0x7fffffffu;

  // ---- radix select: find threshold T such that 64 <= count(bits >= T) <= 256
  unsigned need = KOUT;   // still needed from current bin
  unsigned above = 0;     // count strictly above current bin
  unsigned prefix = 0;    // chosen digit bits so far
  unsigned T = 0;

  for (int level = 0; level < 4; ++level) {
    const int sh = (level == 0) ? 23 : (level == 1) ? 15 : (level == 2) ? 7 : 0;

    for (unsigned i = tid; i < 1024; i += BLK) (&hist[0][0])[i] = 0u;
    __syncthreads();

#pragma unroll
    for (int j = 0; j < 8; ++j) {
      unsigned b = bits[j];
      bool inbin = (level == 0) || ((b >> (sh + 8)) == (prefix >> (sh + 8)));
      if (inbin) atomicAdd(&hist[wv][(b >> sh) & 0xFFu], 1u);
    }
    __syncthreads();

    sscan[tid] = hist[0][tid] + hist[1][tid] + hist[2][tid] + hist[3][tid];
    __syncthreads();
    for (unsigned off = 1; off < 256; off <<= 1) {
      unsigned add = (tid + off < 256u) ? sscan[tid + off] : 0u;
      __syncthreads();
      sscan[tid] += add;
      __syncthreads();
    }

    unsigned suf = sscan[tid];
    unsigned sufn = (tid < 255u) ? sscan[tid + 1] : 0u;
    // suffix is non-increasing; unique d* with suf >= need > sufn
    if (suf >= need && sufn < need) { s_d = tid; s_suf = suf; s_sufn = sufn; }
    __syncthreads();

    unsigned d = s_d, suf_d = s_suf, suf_dn = s_sufn;
    T = prefix | ((unsigned)d << sh);
    if (above + suf_d <= CAND || level == 3) break;  // uniform branch
    above += suf_dn;
    need -= suf_dn;
    prefix = T;
    __syncthreads();
  }

  // ---- compact candidates (bits >= T) as 64-bit keys
  if (tid == 0) s_cnt = 0u;
  __syncthreads();
#pragma unroll
  for (int j = 0; j < 8; ++j) {
    if (bits[j] >= T) {
      unsigned pos = atomicAdd(&s_cnt, 1u);
      if (pos < CAND) {
        unsigned m = (j < 4) ? (tid * 4u + j) : (1024u + tid * 4u + (unsigned)(j - 4));
        // high: abs bits (desc), low: 2047-m so smaller index sorts first on ties
        cand[pos] = ((unsigned long long)bits[j] << 32) | (unsigned long long)(2047u - m);
      }
    }
  }
  __syncthreads();
  unsigned cnt = s_cnt;
  if (cnt > CAND) cnt = CAND;
  if (tid >= cnt) cand[tid] = 0ull;
  unsigned sortN = (cnt <= 128u) ? 128u : 256u;

  // ---- bitonic sort descending over sortN keys
  for (unsigned k = 2; k <= sortN; k <<= 1) {
    for (unsigned j = k >> 1; j > 0; j >>= 1) {
      __syncthreads();
      unsigned i = tid, ixj = i ^ j;
      if (ixj > i && ixj < sortN) {
        unsigned long long x = cand[i], y = cand[ixj];
        if (((i & k) == 0u) ? (x < y) : (x > y)) { cand[i] = y; cand[ixj] = x; }
      }
    }
  }
  __syncthreads();

  // ---- softmax over first k_n, write outputs (threads 0..63 = wave 0)
  if (tid < KOUT) {
    // topk is int per harness convention; sniff a genuine int64 layout just in case.
    bool looks64 = true;
    for (int i = 0; i < 8; ++i) {
      int lo = topk[2 * i];
      int hi = topk[2 * i + 1];
      if (hi != 0 || lo < 1) { looks64 = false; break; }
    }
    int kk = looks64 ? topk[2 * (int)n] : topk[(int)n];
    if (kk > M_COLS) kk = M_COLS;
    if (kk < 0) kk = 0;

    unsigned long long key = cand[tid];
    float val = __uint_as_float((unsigned)(key >> 32));
    unsigned m = 2047u - (unsigned)(key & 0xffffffffu);
    bool valid = (int)tid < kk;

    float mx = __shfl(val, 0, 64);           // lane 0 holds the max (sorted)
    float e = valid ? expf(val - mx) : 0.0f;
    float s = e;
    for (int off = 32; off > 0; off >>= 1) s += __shfl_xor(s, off, 64);
    float w = valid ? (e / s) : 0.0f;

    size_t o = (size_t)row * KOUT + tid;
    out_w[o] = w;
    out_i[o] = valid ? (float)m : 0.0f;
  }
}

extern "C" void kernel_launch(void* const* d_in, const int* in_sizes, int n_in,
                              void* d_out, int out_size, void* d_ws, size_t ws_size,
                              hipStream_t stream) {
  const float* A = (const float*)d_in[0];
  const int* topk = (const int*)d_in[1];
  float* out = (float*)d_out;
  const int NQ = in_sizes[0] / M_COLS;  // N*Q rows (8*2048 = 16384)
  float* out_w = out;
  float* out_i = out + (size_t)NQ * KOUT;
  hipLaunchKernelGGL(topk_route_kernel, dim3(NQ), dim3(BLK), 0, stream,
                     A, topk, out_w, out_i);
}

// Round 2
// 57.701 us; speedup vs baseline: 1.8930x; 1.8930x over previous
//
#include <hip/hip_runtime.h>

#define M_COLS 2048
#define KOUT 64
#define CAND 128
#define BLK 256  // 4 waves per block, 1 row per wave

static __device__ __forceinline__ unsigned long long shfl_xor_u64(
    unsigned long long v, int m) {
  int lo = __shfl_xor((int)(unsigned)v, m, 64);
  int hi = __shfl_xor((int)(unsigned)(v >> 32), m, 64);
  return ((unsigned long long)(unsigned)hi << 32) | (unsigned)lo;
}

// One wave per (n,q) row: exact top-64 by |value| via in-wave radix select on
// the abs bit pattern, in-wave bitonic sort of <=128 candidates (2 keys/lane),
// in-wave softmax. Zero __syncthreads, zero contended atomics.
__global__ __launch_bounds__(BLK) void topk_route_kernel(
    const float* __restrict__ A, const int* __restrict__ topk,
    float* __restrict__ out_w, float* __restrict__ out_i, int NQ, int Q) {
  __shared__ unsigned long long cand[4][CAND];
  __shared__ unsigned s_cnt[4];

  const unsigned tid = threadIdx.x;
  const unsigned wv = tid >> 6, lane = tid & 63u;
  const unsigned row = blockIdx.x * 4u + wv;
  if ((int)row >= NQ) return;
  const unsigned n = row / (unsigned)Q;

  // ---- load 32 elements/lane (8x float4, coalesced within the wave)
  const float4* a4 = (const float4*)(A + (size_t)row * M_COLS);
  unsigned bits[32];
#pragma unroll
  for (int t = 0; t < 8; ++t) {
    float4 v = a4[lane + 64u * (unsigned)t];
    bits[4 * t + 0] = __float_as_uint(v.x) & 0x7fffffffu;
    bits[4 * t + 1] = __float_as_uint(v.y) & 0x7fffffffu;
    bits[4 * t + 2] = __float_as_uint(v.z) & 0x7fffffffu;
    bits[4 * t + 3] = __float_as_uint(v.w) & 0x7fffffffu;
  }

  // init per-wave candidate buffer (no barrier needed: same wave consumes it)
  cand[wv][lane] = 0ull;
  cand[wv][lane + 64u] = 0ull;
  if (lane == 0) s_cnt[wv] = 0u;

  // ---- wave max of abs bits
  unsigned mx = 0u;
#pragma unroll
  for (int j = 0; j < 32; ++j) mx = bits[j] > mx ? bits[j] : mx;
#pragma unroll
  for (int off = 32; off > 0; off >>= 1) {
    unsigned o = (unsigned)__shfl_xor((int)mx, off, 64);
    mx = o > mx ? o : mx;
  }
  const int em = (int)(mx >> 23);

  // ---- 16-bin relative-exponent histogram, packed 2x16-bit in 8 regs
  unsigned cnt[8] = {0u, 0u, 0u, 0u, 0u, 0u, 0u, 0u};
#pragma unroll
  for (int j = 0; j < 32; ++j) {
    int d = em - (int)(bits[j] >> 23);
    if (d > 15) d = 15;
    cnt[d >> 1] += 1u << ((d & 1) << 4);
  }
#pragma unroll
  for (int off = 32; off > 0; off >>= 1) {
#pragma unroll
    for (int q = 0; q < 8; ++q) cnt[q] += (unsigned)__shfl_xor((int)cnt[q], off, 64);
  }

  // ---- pick threshold bin: smallest d with cumcount >= 64
  unsigned cum = 0u, csel = 2048u;
  int jstar = 15;
#pragma unroll
  for (int d = 0; d < 16; ++d) {
    unsigned c = (cnt[d >> 1] >> ((d & 1) << 4)) & 0xffffu;
    cum += c;
    if (cum >= KOUT) { jstar = d; csel = cum; break; }  // uniform across wave
  }
  unsigned T = (jstar < 15) ? ((unsigned)(em - jstar) << 23) : 0u;

  // ---- rare: refine threshold by in-wave binary search until count <= 128
  if (csel > CAND) {
    unsigned lo = T;
    unsigned hi = (jstar > 0) ? ((unsigned)(em - jstar + 1) << 23) : (mx + 1u);
    unsigned clo = csel;
    for (int it = 0; it < 26 && clo > CAND && lo + 1u < hi; ++it) {
      unsigned mid = lo + ((hi - lo) >> 1);
      unsigned c = 0u;
#pragma unroll
      for (int j = 0; j < 32; ++j) c += (bits[j] >= mid) ? 1u : 0u;
#pragma unroll
      for (int off = 32; off > 0; off >>= 1) c += (unsigned)__shfl_xor((int)c, off, 64);
      if (c >= KOUT) { lo = mid; clo = c; } else hi = mid;
    }
    T = lo;
    csel = clo;
  }

  // ---- compact survivors into per-wave LDS (order repaired by sort key)
#pragma unroll
  for (int t = 0; t < 8; ++t) {
#pragma unroll
    for (int c = 0; c < 4; ++c) {
      const int j = 4 * t + c;
      if (bits[j] >= T) {
        unsigned pos = atomicAdd(&s_cnt[wv], 1u);
        if (pos < CAND) {
          unsigned m = (lane + 64u * (unsigned)t) * 4u + (unsigned)c;
          // high: abs bits (desc); low: 2047-m so smaller index sorts first on ties
          cand[wv][pos] =
              ((unsigned long long)bits[j] << 32) | (unsigned long long)(2047u - m);
        }
      }
    }
  }

  // ---- in-wave bitonic sort of 128 keys, 2 per lane (idx = lane + 64*r)
  unsigned long long k0 = cand[wv][lane];
  unsigned long long k1 = cand[wv][lane + 64u];
#pragma unroll
  for (unsigned k = 2; k <= 128u; k <<= 1) {
#pragma unroll
    for (unsigned j = 64u; j > 0; j >>= 1) {
      if (j > (k >> 1)) continue;
      if (j == 64u) {  // only at k==128: exchange k0<->k1, descending
        unsigned long long a = k0 >= k1 ? k0 : k1;
        unsigned long long b = k0 >= k1 ? k1 : k0;
        k0 = a;
        k1 = b;
      } else {
        unsigned long long o0 = shfl_xor_u64(k0, (int)j);
        unsigned long long o1 = shfl_xor_u64(k1, (int)j);
        bool s0 = (lane & j) != 0u;
        bool up0 = (((lane)&k) == 0u) ^ s0;          // keep max?
        bool up1 = (((lane + 64u) & k) == 0u) ^ s0;  // keep max?
        k0 = up0 ? (k0 >= o0 ? k0 : o0) : (k0 >= o0 ? o0 : k0);
        k1 = up1 ? (k1 >= o1 ? k1 : o1) : (k1 >= o1 ? o1 : k1);
      }
    }
  }

  // ---- per-sample k (topk may be int64 or int32 in memory; sniff layout)
  bool looks64 = true;
#pragma unroll
  for (int i = 0; i < 8; ++i) {
    int lo = topk[2 * i], hi = topk[2 * i + 1];
    if (hi != 0 || lo < 1) { looks64 = false; break; }
  }
  int kk = looks64 ? topk[2 * (int)n] : topk[(int)n];
  if (kk > M_COLS) kk = M_COLS;
  if (kk < 0) kk = 0;

  // ---- softmax over first kk entries; rank tid = k0 of lane tid
  float val = __uint_as_float((unsigned)(k0 >> 32));
  unsigned midx = 2047u - (unsigned)(k0 & 0xffffffffull);
  bool valid = (int)lane < kk;

  float vmx = __shfl(val, 0, 64);  // rank 0 = max (sorted desc)
  float e = valid ? expf(val - vmx) : 0.0f;
  float s = e;
#pragma unroll
  for (int off = 32; off > 0; off >>= 1) s += __shfl_xor(s, off, 64);
  float w = valid ? (e / s) : 0.0f;

  size_t o = (size_t)row * KOUT + lane;
  out_w[o] = w;
  out_i[o] = valid ? (float)midx : 0.0f;
}

extern "C" void kernel_launch(void* const* d_in, const int* in_sizes, int n_in,
                              void* d_out, int out_size, void* d_ws, size_t ws_size,
                              hipStream_t stream) {
  const float* A = (const float*)d_in[0];
  const int* topk = (const int*)d_in[1];
  float* out = (float*)d_out;
  const int NQ = in_sizes[0] / M_COLS;  // N*Q rows
  const int N = in_sizes[1] > 0 ? in_sizes[1] : 1;
  const int Q = NQ / N;
  float* out_w = out;
  float* out_i = out + (size_t)NQ * KOUT;
  const int blocks = (NQ + 3) / 4;
  hipLaunchKernelGGL(topk_route_kernel, dim3(blocks), dim3(BLK), 0, stream, A,
                     topk, out_w, out_i, NQ, Q);
}

// Round 3
// 33.862 us; speedup vs baseline: 3.2257x; 1.7040x over previous
//
#include <hip/hip_runtime.h>

#define M_COLS 2048
#define KOUT 64
#define CAND 128
#define BLK 256  // 4 waves/block, 1 row/wave

// xor-lane exchange within 32-lane halves via ds_swizzle (BitMode: (xor<<10)|0x1f)
#define SWZ(v, J) ((unsigned)__builtin_amdgcn_ds_swizzle((int)(v), (((J) << 10) | 0x1f)))

#define WRED_ADD_U(x)                                  \
  do {                                                 \
    x += SWZ(x, 1);                                    \
    x += SWZ(x, 2);                                    \
    x += SWZ(x, 4);                                    \
    x += SWZ(x, 8);                                    \
    x += SWZ(x, 16);                                   \
    x += (unsigned)__shfl_xor((int)(x), 32, 64);       \
  } while (0)

#define WRED_MAX_U(x)                                                  \
  do {                                                                 \
    unsigned _t;                                                       \
    _t = SWZ(x, 1); x = x > _t ? x : _t;                               \
    _t = SWZ(x, 2); x = x > _t ? x : _t;                               \
    _t = SWZ(x, 4); x = x > _t ? x : _t;                               \
    _t = SWZ(x, 8); x = x > _t ? x : _t;                               \
    _t = SWZ(x, 16); x = x > _t ? x : _t;                              \
    _t = (unsigned)__shfl_xor((int)(x), 32, 64); x = x > _t ? x : _t;  \
  } while (0)

#define WSCAN_INC_U(x)                                  \
  do {                                                  \
    unsigned _y;                                        \
    _y = __shfl_up(x, 1, 64);  if (lane >= 1)  x += _y; \
    _y = __shfl_up(x, 2, 64);  if (lane >= 2)  x += _y; \
    _y = __shfl_up(x, 4, 64);  if (lane >= 4)  x += _y; \
    _y = __shfl_up(x, 8, 64);  if (lane >= 8)  x += _y; \
    _y = __shfl_up(x, 16, 64); if (lane >= 16) x += _y; \
    _y = __shfl_up(x, 32, 64); if (lane >= 32) x += _y; \
  } while (0)

#define SHX64_S(dst, src, J)                         \
  do {                                               \
    unsigned _lo = SWZ((unsigned)(src), J);          \
    unsigned _hi = SWZ((unsigned)((src) >> 32), J);  \
    dst = ((unsigned long long)_hi << 32) | _lo;     \
  } while (0)
#define SHX64_W(dst, src)                                                        \
  do {                                                                           \
    unsigned _lo = (unsigned)__shfl_xor((int)(unsigned)(src), 32, 64);           \
    unsigned _hi = (unsigned)__shfl_xor((int)(unsigned)((src) >> 32), 32, 64);   \
    dst = ((unsigned long long)_hi << 32) | _lo;                                 \
  } while (0)

// one stage of dual 64-sort: k0 descending, k1 ascending (mirrored comparators)
#define STEP_A_S(K, J)                          \
  do {                                          \
    unsigned long long o0, o1;                  \
    SHX64_S(o0, k0, J);                         \
    SHX64_S(o1, k1, J);                         \
    bool s0 = (lane & (J)) != 0u;               \
    bool up0 = ((lane & (K)) == 0u) ^ s0;       \
    k0 = (up0 == (k0 >= o0)) ? k0 : o0;         \
    k1 = (up0 == (k1 >= o1)) ? o1 : k1;         \
  } while (0)
#define STEP_A_W(K)                             \
  do {                                          \
    unsigned long long o0, o1;                  \
    SHX64_W(o0, k0);                            \
    SHX64_W(o1, k1);                            \
    bool s0 = (lane & 32u) != 0u;               \
    bool up0 = ((lane & (K)) == 0u) ^ s0;       \
    k0 = (up0 == (k0 >= o0)) ? k0 : o0;         \
    k1 = (up0 == (k1 >= o1)) ? o1 : k1;         \
  } while (0)

// descending bitonic merge stage on av
#define STEP_B_S(J)                             \
  do {                                          \
    unsigned long long o;                       \
    SHX64_S(o, av, J);                          \
    bool up = ((lane & (J)) == 0u);             \
    av = (up == (av >= o)) ? av : o;            \
  } while (0)
#define STEP_B_W()                              \
  do {                                          \
    unsigned long long o;                       \
    SHX64_W(o, av);                             \
    bool up = ((lane & 32u) == 0u);             \
    av = (up == (av >= o)) ? av : o;            \
  } while (0)

__global__ __launch_bounds__(BLK) void topk_route_kernel(
    const float* __restrict__ A, const int* __restrict__ topk,
    float* __restrict__ out_w, float* __restrict__ out_i, int NQ, int Q, int N) {
  __shared__ unsigned long long cand[4][CAND];

  const unsigned tid = threadIdx.x;
  const unsigned wv = tid >> 6, lane = tid & 63u;
  const unsigned row = blockIdx.x * 4u + wv;
  if ((int)row >= NQ) return;
  const unsigned n = row / (unsigned)Q;

  // ---- load 32 elements/lane (8x float4, coalesced within the wave)
  const float4* a4 = (const float4*)(A + (size_t)row * M_COLS);
  unsigned bits[32];
#pragma unroll
  for (int t = 0; t < 8; ++t) {
    float4 v = a4[lane + 64u * (unsigned)t];
    bits[4 * t + 0] = __float_as_uint(v.x) & 0x7fffffffu;
    bits[4 * t + 1] = __float_as_uint(v.y) & 0x7fffffffu;
    bits[4 * t + 2] = __float_as_uint(v.z) & 0x7fffffffu;
    bits[4 * t + 3] = __float_as_uint(v.w) & 0x7fffffffu;
  }

  // zero pad slots of the upper half (lower 64 always written: csel >= 64)
  cand[wv][lane + 64u] = 0ull;

  // ---- wave max of abs bits
  unsigned mx = 0u;
#pragma unroll
  for (int j = 0; j < 32; ++j) mx = bits[j] > mx ? bits[j] : mx;
  WRED_MAX_U(mx);
  const int em = (int)(mx >> 23);

  auto wcount = [&](unsigned T) -> unsigned {
    unsigned c = 0u;
#pragma unroll
    for (int j = 0; j < 32; ++j) c += (bits[j] >= T) ? 1u : 0u;
    WRED_ADD_U(c);
    return c;
  };

  // ---- threshold search: invariant count(>=lo) = csel >= 64 > count(>=hi)
  unsigned lo = 0u, hi = mx + 1u, csel = (unsigned)M_COLS;
  bool found = false;
#pragma unroll
  for (int d = 0; d < 3; ++d) {
    if (!found) {
      int e = em - d;
      unsigned T = (e > 0) ? ((unsigned)e << 23) : 0u;
      unsigned c = wcount(T);
      if (c >= KOUT) { lo = T; csel = c; found = true; }
      else hi = T;
    }
  }
  // binary refine (rare: typical rows have 64 <= csel <= 128 at d=0)
  while (csel > CAND && lo + 1u < hi) {
    unsigned mid = lo + ((hi - lo) >> 1);
    unsigned c = wcount(mid);
    if (c >= KOUT) { lo = mid; csel = c; } else hi = mid;
  }

  // ---- keep mask (per-lane bitmask over 32 elements)
  unsigned keep = 0u;
  if (csel <= CAND) {
#pragma unroll
    for (int j = 0; j < 32; ++j) keep |= (bits[j] >= lo) ? (1u << j) : 0u;
  } else {
    // ultra-rare: >128 keys tie at bits==lo. Keep all > lo, plus the
    // smallest-index ties up to capacity (index order m = 256t + 4*lane + c).
#pragma unroll
    for (int j = 0; j < 32; ++j) keep |= (bits[j] >= hi) ? (1u << j) : 0u;
    unsigned cgt = __popc(keep);
    WRED_ADD_U(cgt);
    unsigned cap = CAND - cgt;
    unsigned run = 0u;
#pragma unroll
    for (int t = 0; t < 8; ++t) {
      unsigned f = 0u;
#pragma unroll
      for (int c = 0; c < 4; ++c) f |= (bits[4 * t + c] == lo) ? (1u << c) : 0u;
      unsigned tc = __popc(f);
      unsigned inc = tc;
      WSCAN_INC_U(inc);
      unsigned r = run + inc - tc;
#pragma unroll
      for (int c = 0; c < 4; ++c) {
        if (f & (1u << c)) {
          if (r < cap) keep |= 1u << (4 * t + c);
          ++r;
        }
      }
      run += (unsigned)__shfl((int)inc, 63, 64);
    }
  }

  // ---- prefix-scan compaction into per-wave LDS (no atomics)
  unsigned sl = __popc(keep);
  unsigned inc = sl;
  WSCAN_INC_U(inc);
  unsigned p = inc - sl;  // exclusive prefix = write base
#pragma unroll
  for (int t = 0; t < 8; ++t) {
#pragma unroll
    for (int c = 0; c < 4; ++c) {
      const int j = 4 * t + c;
      if (keep & (1u << j)) {
        unsigned m = 4u * (lane + 64u * (unsigned)t) + (unsigned)c;
        if (p < CAND)
          cand[wv][p] =
              ((unsigned long long)bits[j] << 32) | (unsigned long long)(2047u - m);
        ++p;
      }
    }
  }

  // ---- sort: k0 desc + k1 asc (21 stages), per-lane exchange, merge top half (6)
  unsigned long long k0 = cand[wv][lane];
  unsigned long long k1 = cand[wv][lane + 64u];
  STEP_A_S(2, 1);
  STEP_A_S(4, 2);  STEP_A_S(4, 1);
  STEP_A_S(8, 4);  STEP_A_S(8, 2);  STEP_A_S(8, 1);
  STEP_A_S(16, 8); STEP_A_S(16, 4); STEP_A_S(16, 2); STEP_A_S(16, 1);
  STEP_A_S(32, 16); STEP_A_S(32, 8); STEP_A_S(32, 4); STEP_A_S(32, 2); STEP_A_S(32, 1);
  STEP_A_W(64); STEP_A_S(64, 16); STEP_A_S(64, 8); STEP_A_S(64, 4); STEP_A_S(64, 2); STEP_A_S(64, 1);

  unsigned long long av = k0 >= k1 ? k0 : k1;  // bitonic, holds the top-64 set
  STEP_B_W();
  STEP_B_S(16); STEP_B_S(8); STEP_B_S(4); STEP_B_S(2); STEP_B_S(1);

  // ---- per-sample k (topk may be int64 or int32 in memory; sniff layout)
  bool looks64 = true;
  int sniffn = N < 8 ? N : 8;
  for (int i = 0; i < sniffn; ++i) {
    int l = topk[2 * i], h = topk[2 * i + 1];
    if (h != 0 || l < 1) { looks64 = false; break; }
  }
  int kk = looks64 ? topk[2 * (int)n] : topk[(int)n];
  if (kk > M_COLS) kk = M_COLS;
  if (kk < 0) kk = 0;

  // ---- softmax over first kk entries; lane = rank (sorted desc)
  float val = __uint_as_float((unsigned)(av >> 32));
  unsigned midx = 2047u - (unsigned)(av & 0xffffffffull);
  bool valid = (int)lane < kk;

  float vmx = __shfl(val, 0, 64);
  float e = valid ? __expf(val - vmx) : 0.0f;
  float s = e;
  s += __uint_as_float(SWZ(__float_as_uint(s), 1));
  s += __uint_as_float(SWZ(__float_as_uint(s), 2));
  s += __uint_as_float(SWZ(__float_as_uint(s), 4));
  s += __uint_as_float(SWZ(__float_as_uint(s), 8));
  s += __uint_as_float(SWZ(__float_as_uint(s), 16));
  s += __shfl_xor(s, 32, 64);
  float w = valid ? (e / s) : 0.0f;

  size_t o = (size_t)row * KOUT + lane;
  out_w[o] = w;
  out_i[o] = valid ? (float)midx : 0.0f;
}

extern "C" void kernel_launch(void* const* d_in, const int* in_sizes, int n_in,
                              void* d_out, int out_size, void* d_ws, size_t ws_size,
                              hipStream_t stream) {
  const float* A = (const float*)d_in[0];
  const int* topk = (const int*)d_in[1];
  float* out = (float*)d_out;
  const int NQ = in_sizes[0] / M_COLS;
  const int N = in_sizes[1] > 0 ? in_sizes[1] : 1;
  const int Q = NQ / N;
  float* out_w = out;
  float* out_i = out + (size_t)NQ * KOUT;
  const int blocks = (NQ + 3) / 4;
  hipLaunchKernelGGL(topk_route_kernel, dim3(blocks), dim3(BLK), 0, stream, A,
                     topk, out_w, out_i, NQ, Q, N);
}

// Round 4
// 29.997 us; speedup vs baseline: 3.6413x; 1.1288x over previous
//
#include <hip/hip_runtime.h>

#define M_COLS 2048
#define KOUT 64
#define CAND 128
#define BLK 256  // 4 waves/block, 1 row/wave

// ---- DPP move (pure VALU, no LDS pipe): old for masked/invalid lanes
#define DPPU(old, src, ctrl, rmask) \
  ((unsigned)__builtin_amdgcn_update_dpp((int)(old), (int)(src), (ctrl), (rmask), 0xF, false))
#define RDL(x, l) ((unsigned)__builtin_amdgcn_readlane((int)(x), (l)))

// canonical wave64 inclusive scans: row_shr 1/2/4/8 then bcast15 (rows 1,3), bcast31 (rows 2,3)
#define SCAN_ADD_U(x)              \
  do {                             \
    x += DPPU(0u, x, 0x111, 0xF);  \
    x += DPPU(0u, x, 0x112, 0xF);  \
    x += DPPU(0u, x, 0x114, 0xF);  \
    x += DPPU(0u, x, 0x118, 0xF);  \
    x += DPPU(0u, x, 0x142, 0xA);  \
    x += DPPU(0u, x, 0x143, 0xC);  \
  } while (0)

#define SCAN_MAX_U(x)                                  \
  do {                                                 \
    unsigned _t;                                       \
    _t = DPPU(0u, x, 0x111, 0xF); x = x > _t ? x : _t; \
    _t = DPPU(0u, x, 0x112, 0xF); x = x > _t ? x : _t; \
    _t = DPPU(0u, x, 0x114, 0xF); x = x > _t ? x : _t; \
    _t = DPPU(0u, x, 0x118, 0xF); x = x > _t ? x : _t; \
    _t = DPPU(0u, x, 0x142, 0xA); x = x > _t ? x : _t; \
    _t = DPPU(0u, x, 0x143, 0xC); x = x > _t ? x : _t; \
  } while (0)

#define SCAN_ADD_F(x)                                                \
  do {                                                               \
    x += __uint_as_float(DPPU(0u, __float_as_uint(x), 0x111, 0xF));  \
    x += __uint_as_float(DPPU(0u, __float_as_uint(x), 0x112, 0xF));  \
    x += __uint_as_float(DPPU(0u, __float_as_uint(x), 0x114, 0xF));  \
    x += __uint_as_float(DPPU(0u, __float_as_uint(x), 0x118, 0xF));  \
    x += __uint_as_float(DPPU(0u, __float_as_uint(x), 0x142, 0xA));  \
    x += __uint_as_float(DPPU(0u, __float_as_uint(x), 0x143, 0xC));  \
  } while (0)

// xor-lane exchange within 32-lane halves via ds_swizzle (BitMode: (xor<<10)|0x1f)
#define SWZ(v, J) ((unsigned)__builtin_amdgcn_ds_swizzle((int)(v), (((J) << 10) | 0x1f)))

#define SHX64_S(dst, src, J)                        \
  do {                                              \
    unsigned _lo = SWZ((unsigned)(src), J);         \
    unsigned _hi = SWZ((unsigned)((src) >> 32), J); \
    dst = ((unsigned long long)_hi << 32) | _lo;    \
  } while (0)
#define SHX64_W(dst, src)                                                      \
  do {                                                                         \
    unsigned _lo = (unsigned)__shfl_xor((int)(unsigned)(src), 32, 64);         \
    unsigned _hi = (unsigned)__shfl_xor((int)(unsigned)((src) >> 32), 32, 64); \
    dst = ((unsigned long long)_hi << 32) | _lo;                               \
  } while (0)

// one stage of dual 64-sort: k0 descending, k1 ascending (mirrored comparators)
#define STEP_A_S(K, J)                    \
  do {                                    \
    unsigned long long o0, o1;            \
    SHX64_S(o0, k0, J);                   \
    SHX64_S(o1, k1, J);                   \
    bool s0 = (lane & (J)) != 0u;         \
    bool up0 = ((lane & (K)) == 0u) ^ s0; \
    k0 = (up0 == (k0 >= o0)) ? k0 : o0;   \
    k1 = (up0 == (k1 >= o1)) ? o1 : k1;   \
  } while (0)
#define STEP_A_W(K)                       \
  do {                                    \
    unsigned long long o0, o1;            \
    SHX64_W(o0, k0);                      \
    SHX64_W(o1, k1);                      \
    bool s0 = (lane & 32u) != 0u;         \
    bool up0 = ((lane & (K)) == 0u) ^ s0; \
    k0 = (up0 == (k0 >= o0)) ? k0 : o0;   \
    k1 = (up0 == (k1 >= o1)) ? o1 : k1;   \
  } while (0)

// descending bitonic merge stage on av
#define STEP_B_S(J)                   \
  do {                                \
    unsigned long long o;             \
    SHX64_S(o, av, J);                \
    bool up = ((lane & (J)) == 0u);   \
    av = (up == (av >= o)) ? av : o;  \
  } while (0)
#define STEP_B_W()                    \
  do {                                \
    unsigned long long o;             \
    SHX64_W(o, av);                   \
    bool up = ((lane & 32u) == 0u);   \
    av = (up == (av >= o)) ? av : o;  \
  } while (0)

__global__ __launch_bounds__(BLK) void topk_route_kernel(
    const float* __restrict__ A, const int* __restrict__ topk,
    float* __restrict__ out_w, float* __restrict__ out_i, int NQ, int Q, int N) {
  __shared__ unsigned long long cand[4][CAND];

  const unsigned tid = threadIdx.x;
  const unsigned wv = tid >> 6, lane = tid & 63u;
  const unsigned row = blockIdx.x * 4u + wv;
  if ((int)row >= NQ) return;
  const unsigned n = row / (unsigned)Q;

  // per-sample k early (L2-resident; topk may be int64 or int32 — sniff layout)
  bool looks64 = true;
  int sniffn = N < 8 ? N : 8;
  for (int i = 0; i < sniffn; ++i) {
    int l = topk[2 * i], h = topk[2 * i + 1];
    if (h != 0 || l < 1) { looks64 = false; break; }
  }
  int kk = looks64 ? topk[2 * (int)n] : topk[(int)n];
  kk = kk > M_COLS ? M_COLS : (kk < 0 ? 0 : kk);

  // ---- load 32 elements/lane (8x float4, coalesced within the wave)
  const float4* a4 = (const float4*)(A + (size_t)row * M_COLS);
  unsigned bits[32];
#pragma unroll
  for (int t = 0; t < 8; ++t) {
    float4 v = a4[lane + 64u * (unsigned)t];
    bits[4 * t + 0] = __float_as_uint(v.x) & 0x7fffffffu;
    bits[4 * t + 1] = __float_as_uint(v.y) & 0x7fffffffu;
    bits[4 * t + 2] = __float_as_uint(v.z) & 0x7fffffffu;
    bits[4 * t + 3] = __float_as_uint(v.w) & 0x7fffffffu;
  }

  // zero pad slots of the upper half (lower 64 always overwritten: csel >= 64)
  cand[wv][lane + 64u] = 0ull;

  // ---- wave max -> scalar em
  unsigned mx = bits[0];
#pragma unroll
  for (int j = 1; j < 32; ++j) mx = bits[j] > mx ? bits[j] : mx;
  SCAN_MAX_U(mx);
  mx = RDL(mx, 63);  // uniform
  const int em = (int)(mx >> 23);

  // attempt(T): keep-mask + popc + DPP scan + uniform total
  unsigned keep = 0u, sl = 0u, inc = 0u, csel = 0u;
  auto attempt = [&](unsigned T) {
    unsigned k = 0u;
#pragma unroll
    for (int j = 31; j >= 0; --j) k = (k << 1) | (unsigned)(bits[j] >= T);
    keep = k;
    sl = __popc(k);
    inc = sl;
    SCAN_ADD_U(inc);
    csel = RDL(inc, 63);
  };

  // ---- probe em, em-1, em-2 (T=0 always qualifies: count=2048)
  unsigned lo, hi = mx + 1u;
  {
    unsigned T = (em > 0) ? ((unsigned)em << 23) : 0u;
    attempt(T); lo = T;
    if (csel < KOUT) {
      hi = T;
      T = (em - 1 > 0) ? ((unsigned)(em - 1) << 23) : 0u;
      attempt(T); lo = T;
      if (csel < KOUT) {
        hi = T;
        T = (em - 2 > 0) ? ((unsigned)(em - 2) << 23) : 0u;
        attempt(T); lo = T;
        if (csel < KOUT) { hi = T; attempt(0u); lo = 0u; }
      }
    }
  }

  // ---- rare: binary refine until count(>=lo) <= 128 (invariant count(>=hi) < 64)
  {
    unsigned csel_lo = csel, lastT = lo;
    while (csel_lo > CAND && lo + 1u < hi) {
      unsigned mid = lo + ((hi - lo) >> 1);
      attempt(mid); lastT = mid;
      if (csel >= KOUT) { lo = mid; csel_lo = csel; } else hi = mid;
    }
    if (lastT != lo) attempt(lo);
  }

  // ---- ultra-rare: >128 ties at lo (== V64): keep all > lo + smallest-index ties
  if (csel > CAND) {
    unsigned kgt = 0u;
#pragma unroll
    for (int j = 31; j >= 0; --j) kgt = (kgt << 1) | (unsigned)(bits[j] >= hi);
    unsigned slgt = __popc(kgt), incgt = slgt;
    SCAN_ADD_U(incgt);
    unsigned cgt = RDL(incgt, 63);
    unsigned cap = CAND - cgt;
    keep = kgt;
    unsigned run = 0u;
#pragma unroll
    for (int t = 0; t < 8; ++t) {
      unsigned f = 0u;
#pragma unroll
      for (int c = 3; c >= 0; --c) f = (f << 1) | (unsigned)(bits[4 * t + c] == lo);
      unsigned tc = __popc(f), it = tc;
      SCAN_ADD_U(it);
      unsigned base = run + it - tc;
#pragma unroll
      for (int c = 0; c < 4; ++c) {
        if (f & (1u << c)) {
          if (base < cap) keep |= 1u << (4 * t + c);
          ++base;
        }
      }
      run += RDL(it, 63);
    }
    sl = __popc(keep);
    inc = sl;
    SCAN_ADD_U(inc);
    csel = RDL(inc, 63);
  }

  // ---- prefix-scan compaction into per-wave LDS (no atomics, csel <= 128)
  unsigned p = inc - sl;  // exclusive prefix = write base
  const unsigned lobase = 2047u - 4u * lane;
  unsigned long long* cw = &cand[wv][0];
#pragma unroll
  for (int j = 0; j < 32; ++j) {
    if (keep & (1u << j)) {
      cw[p] = ((unsigned long long)bits[j] << 32) |
              (unsigned long long)(lobase - (unsigned)((j >> 2) * 256 + (j & 3)));
      ++p;
    }
  }

  // ---- sort: k0 desc + k1 asc (21 dual stages), local exchange, merge top half
  unsigned long long k0 = cand[wv][lane];
  unsigned long long k1 = cand[wv][lane + 64u];
  STEP_A_S(2, 1);
  STEP_A_S(4, 2);  STEP_A_S(4, 1);
  STEP_A_S(8, 4);  STEP_A_S(8, 2);  STEP_A_S(8, 1);
  STEP_A_S(16, 8); STEP_A_S(16, 4); STEP_A_S(16, 2); STEP_A_S(16, 1);
  STEP_A_S(32, 16); STEP_A_S(32, 8); STEP_A_S(32, 4); STEP_A_S(32, 2); STEP_A_S(32, 1);
  STEP_A_W(64); STEP_A_S(64, 16); STEP_A_S(64, 8); STEP_A_S(64, 4); STEP_A_S(64, 2); STEP_A_S(64, 1);

  unsigned long long av = k0 >= k1 ? k0 : k1;  // bitonic; holds the top-64 set
  STEP_B_W();
  STEP_B_S(16); STEP_B_S(8); STEP_B_S(4); STEP_B_S(2); STEP_B_S(1);

  // ---- softmax over first kk entries; lane = rank (sorted desc)
  float val = __uint_as_float((unsigned)(av >> 32));
  unsigned midx = 2047u - (unsigned)(av & 0xffffffffull);
  bool valid = (int)lane < kk;

  float vmx = __uint_as_float((unsigned)__builtin_amdgcn_readfirstlane((int)(unsigned)(av >> 32)));
  float e = valid ? __expf(val - vmx) : 0.0f;
  float s = e;
  SCAN_ADD_F(s);
  float stot = __uint_as_float(RDL(__float_as_uint(s), 63));
  float w = valid ? (e / stot) : 0.0f;

  size_t o = (size_t)row * KOUT + lane;
  out_w[o] = w;
  out_i[o] = valid ? (float)midx : 0.0f;
}

extern "C" void kernel_launch(void* const* d_in, const int* in_sizes, int n_in,
                              void* d_out, int out_size, void* d_ws, size_t ws_size,
                              hipStream_t stream) {
  const float* A = (const float*)d_in[0];
  const int* topk = (const int*)d_in[1];
  float* out = (float*)d_out;
  const int NQ = in_sizes[0] / M_COLS;
  const int N = in_sizes[1] > 0 ? in_sizes[1] : 1;
  const int Q = NQ / N;
  float* out_w = out;
  float* out_i = out + (size_t)NQ * KOUT;
  const int blocks = (NQ + 3) / 4;
  hipLaunchKernelGGL(topk_route_kernel, dim3(blocks), dim3(BLK), 0, stream, A,
                     topk, out_w, out_i, NQ, Q, N);
}

// Round 5
// 29.662 us; speedup vs baseline: 3.6824x; 1.0113x over previous
//
#include <hip/hip_runtime.h>

#define M_COLS 2048
#define KOUT 64
#define CAND 128
#define BLK 256  // 4 waves/block, 1 row/wave

typedef unsigned long long u64;

// ---- DPP move (pure VALU): quad_perm / row_shr / row_bcast
#define DPPU(old, src, ctrl, rmask) \
  ((unsigned)__builtin_amdgcn_update_dpp((int)(old), (int)(src), (ctrl), (rmask), 0xF, false))
#define RDL(x, l) ((unsigned)__builtin_amdgcn_readlane((int)(x), (l)))

// canonical wave64 inclusive scans: row_shr 1/2/4/8, bcast15 (rows 1,3), bcast31 (rows 2,3)
#define SCAN_ADD_U(x)             \
  do {                            \
    x += DPPU(0u, x, 0x111, 0xF); \
    x += DPPU(0u, x, 0x112, 0xF); \
    x += DPPU(0u, x, 0x114, 0xF); \
    x += DPPU(0u, x, 0x118, 0xF); \
    x += DPPU(0u, x, 0x142, 0xA); \
    x += DPPU(0u, x, 0x143, 0xC); \
  } while (0)

#define SCAN_MAX_U(x)                                  \
  do {                                                 \
    unsigned _t;                                       \
    _t = DPPU(0u, x, 0x111, 0xF); x = x > _t ? x : _t; \
    _t = DPPU(0u, x, 0x112, 0xF); x = x > _t ? x : _t; \
    _t = DPPU(0u, x, 0x114, 0xF); x = x > _t ? x : _t; \
    _t = DPPU(0u, x, 0x118, 0xF); x = x > _t ? x : _t; \
    _t = DPPU(0u, x, 0x142, 0xA); x = x > _t ? x : _t; \
    _t = DPPU(0u, x, 0x143, 0xC); x = x > _t ? x : _t; \
  } while (0)

#define SCAN_ADD_F(x)                                               \
  do {                                                              \
    x += __uint_as_float(DPPU(0u, __float_as_uint(x), 0x111, 0xF)); \
    x += __uint_as_float(DPPU(0u, __float_as_uint(x), 0x112, 0xF)); \
    x += __uint_as_float(DPPU(0u, __float_as_uint(x), 0x114, 0xF)); \
    x += __uint_as_float(DPPU(0u, __float_as_uint(x), 0x118, 0xF)); \
    x += __uint_as_float(DPPU(0u, __float_as_uint(x), 0x142, 0xA)); \
    x += __uint_as_float(DPPU(0u, __float_as_uint(x), 0x143, 0xC)); \
  } while (0)

// xor-lane exchange within 32-lane halves via ds_swizzle (BitMode: (xor<<10)|0x1f)
#define SWZ(v, J) ((unsigned)__builtin_amdgcn_ds_swizzle((int)(v), (((J) << 10) | 0x1f)))

// u64 partner fetch: ds_swizzle (J=4,8,16), DPP quad_perm (J=1,2), bpermute (J=32)
#define EX_S(dst, src, J)                           \
  do {                                              \
    unsigned _lo = SWZ((unsigned)(src), J);         \
    unsigned _hi = SWZ((unsigned)((src) >> 32), J); \
    dst = ((u64)_hi << 32) | _lo;                   \
  } while (0)
#define EX_D(dst, src, CTRL)                             \
  do {                                                   \
    unsigned _lo = DPPU(0u, (unsigned)(src), CTRL, 0xF); \
    unsigned _hi = DPPU(0u, (unsigned)((src) >> 32), CTRL, 0xF); \
    dst = ((u64)_hi << 32) | _lo;                        \
  } while (0)
#define EX_W(dst, src)                                                         \
  do {                                                                         \
    unsigned _lo = (unsigned)__shfl_xor((int)(unsigned)(src), 32, 64);         \
    unsigned _hi = (unsigned)__shfl_xor((int)(unsigned)((src) >> 32), 32, 64); \
    dst = ((u64)_hi << 32) | _lo;                                              \
  } while (0)

// dual compare-exchange: k0 descending, k1 ascending (mirrored)
#define CMPSEL(up)                        \
  do {                                    \
    k0 = ((k0 >= o0) == (up)) ? k0 : o0;  \
    k1 = ((k1 >= o1) == (up)) ? o1 : k1;  \
  } while (0)

#define STEP_A_S(J, UP) do { u64 o0, o1; EX_S(o0, k0, J); EX_S(o1, k1, J); CMPSEL(UP); } while (0)
#define STEP_A_D(CTRL, UP) do { u64 o0, o1; EX_D(o0, k0, CTRL); EX_D(o1, k1, CTRL); CMPSEL(UP); } while (0)
#define STEP_A_W(UP) do { u64 o0, o1; EX_W(o0, k0); EX_W(o1, k1); CMPSEL(UP); } while (0)

// descending bitonic merge stage on av
#define STEP_B_S(J, UP) do { u64 o; EX_S(o, av, J); av = ((av >= o) == (UP)) ? av : o; } while (0)
#define STEP_B_D(CTRL, UP) do { u64 o; EX_D(o, av, CTRL); av = ((av >= o) == (UP)) ? av : o; } while (0)
#define STEP_B_W(UP) do { u64 o; EX_W(o, av); av = ((av >= o) == (UP)) ? av : o; } while (0)

__global__ __launch_bounds__(BLK) void topk_route_kernel(
    const float* __restrict__ A, const int* __restrict__ topk,
    float* __restrict__ out_w, float* __restrict__ out_i, int NQ, int Q, int N) {
  __shared__ u64 cand[4][CAND];

  const unsigned tid = threadIdx.x;
  const unsigned wv = tid >> 6, lane = tid & 63u;
  const unsigned row = blockIdx.x * 4u + wv;
  if ((int)row >= NQ) return;
  const unsigned n = row / (unsigned)Q;

  // ---- issue row loads FIRST (8x float4, coalesced within the wave)
  const float4* a4 = (const float4*)(A + (size_t)row * M_COLS);
  float4 v[8];
#pragma unroll
  for (int t = 0; t < 8; ++t) v[t] = a4[lane + 64u * (unsigned)t];

  // ---- branch-free topk sniff while row loads are in flight (int64 vs int32)
  int kk;
  if (N >= 8) {
    const int4* t4 = (const int4*)topk;
    int4 a = t4[0], b = t4[1], c = t4[2], d = t4[3];
    int k64 = topk[2 * (int)n], k32 = topk[(int)n];
    bool looks64 = (a.y == 0) & (a.w == 0) & (b.y == 0) & (b.w == 0) &
                   (c.y == 0) & (c.w == 0) & (d.y == 0) & (d.w == 0) &
                   (a.x >= 1) & (a.z >= 1) & (b.x >= 1) & (b.z >= 1) &
                   (c.x >= 1) & (c.z >= 1) & (d.x >= 1) & (d.z >= 1);
    kk = looks64 ? k64 : k32;
  } else {
    bool looks64 = true;
    for (int i = 0; i < N; ++i) {
      int l = topk[2 * i], h = topk[2 * i + 1];
      if (h != 0 || l < 1) { looks64 = false; break; }
    }
    kk = looks64 ? topk[2 * (int)n] : topk[(int)n];
  }
  kk = kk > M_COLS ? M_COLS : (kk < 0 ? 0 : kk);

  unsigned bits[32];
#pragma unroll
  for (int t = 0; t < 8; ++t) {
    bits[4 * t + 0] = __float_as_uint(v[t].x) & 0x7fffffffu;
    bits[4 * t + 1] = __float_as_uint(v[t].y) & 0x7fffffffu;
    bits[4 * t + 2] = __float_as_uint(v[t].z) & 0x7fffffffu;
    bits[4 * t + 3] = __float_as_uint(v[t].w) & 0x7fffffffu;
  }

  // zero pad slots of the upper half (lower 64 always overwritten: csel >= 64)
  cand[wv][lane + 64u] = 0ull;

  // ---- wave max -> uniform em
  unsigned mx = bits[0];
#pragma unroll
  for (int j = 1; j < 32; ++j) mx = bits[j] > mx ? bits[j] : mx;
  SCAN_MAX_U(mx);
  mx = RDL(mx, 63);
  const int em = (int)(mx >> 23);

  // attempt(T): keep-mask (4 independent 8-chains) + popc + DPP scan + total
  unsigned keep = 0u, sl = 0u, inc = 0u, csel = 0u;
  auto attempt = [&](unsigned T) {
    unsigned q0 = 0u, q1 = 0u, q2 = 0u, q3 = 0u;
#pragma unroll
    for (int j = 7; j >= 0; --j) {
      q0 = q0 + q0 + (unsigned)(bits[j] >= T);
      q1 = q1 + q1 + (unsigned)(bits[8 + j] >= T);
      q2 = q2 + q2 + (unsigned)(bits[16 + j] >= T);
      q3 = q3 + q3 + (unsigned)(bits[24 + j] >= T);
    }
    keep = q0 | (q1 << 8) | (q2 << 16) | (q3 << 24);
    sl = __popc(keep);
    inc = sl;
    SCAN_ADD_U(inc);
    csel = RDL(inc, 63);
  };

  // ---- probe em, em-1, em-2 (T=0 always qualifies: count=2048)
  unsigned lo, hi = mx + 1u;
  {
    unsigned T = (em > 0) ? ((unsigned)em << 23) : 0u;
    attempt(T); lo = T;
    if (csel < KOUT) {
      hi = T;
      T = (em - 1 > 0) ? ((unsigned)(em - 1) << 23) : 0u;
      attempt(T); lo = T;
      if (csel < KOUT) {
        hi = T;
        T = (em - 2 > 0) ? ((unsigned)(em - 2) << 23) : 0u;
        attempt(T); lo = T;
        if (csel < KOUT) { hi = T; attempt(0u); lo = 0u; }
      }
    }
  }

  // ---- rare: binary refine until 64 <= count(>=lo) <= 128
  {
    unsigned csel_lo = csel, lastT = lo;
    while (csel_lo > CAND && lo + 1u < hi) {
      unsigned mid = lo + ((hi - lo) >> 1);
      attempt(mid); lastT = mid;
      if (csel >= KOUT) { lo = mid; csel_lo = csel; } else hi = mid;
    }
    if (lastT != lo) attempt(lo);
  }

  // ---- ultra-rare: >128 ties at lo: keep all > lo + smallest-index ties
  if (csel > CAND) {
    unsigned kgt = 0u;
#pragma unroll
    for (int j = 31; j >= 0; --j) kgt = (kgt << 1) | (unsigned)(bits[j] >= hi);
    unsigned slgt = __popc(kgt), incgt = slgt;
    SCAN_ADD_U(incgt);
    unsigned cgt = RDL(incgt, 63);
    unsigned cap = CAND - cgt;
    keep = kgt;
    unsigned run = 0u;
#pragma unroll
    for (int t = 0; t < 8; ++t) {
      unsigned f = 0u;
#pragma unroll
      for (int c = 3; c >= 0; --c) f = (f << 1) | (unsigned)(bits[4 * t + c] == lo);
      unsigned tc = __popc(f), it = tc;
      SCAN_ADD_U(it);
      unsigned base = run + it - tc;
#pragma unroll
      for (int c = 0; c < 4; ++c) {
        if (f & (1u << c)) {
          if (base < cap) keep |= 1u << (4 * t + c);
          ++base;
        }
      }
      run += RDL(it, 63);
    }
    sl = __popc(keep);
    inc = sl;
    SCAN_ADD_U(inc);
    csel = RDL(inc, 63);
  }

  // ---- prefix-scan compaction into per-wave LDS (no atomics, csel <= 128)
  unsigned p = inc - sl;  // exclusive prefix = write base
  const unsigned lobase = 2047u - 4u * lane;
  u64* cw = &cand[wv][0];
#pragma unroll
  for (int j = 0; j < 32; ++j) {
    if (keep & (1u << j)) {
      cw[p] = ((u64)bits[j] << 32) |
              (u64)(lobase - (unsigned)((j >> 2) * 256 + (j & 3)));
      ++p;
    }
  }

  // ---- per-stage comparator flags from lane bits
  const bool b1 = (lane & 1u) != 0u, b2 = (lane & 2u) != 0u, b4 = (lane & 4u) != 0u;
  const bool b8 = (lane & 8u) != 0u, b16 = (lane & 16u) != 0u, b32 = (lane & 32u) != 0u;

  // ---- sort: k0 desc + k1 asc (21 dual stages), local exchange, merge top half
  u64 k0 = cand[wv][lane];
  u64 k1 = cand[wv][lane + 64u];
  // k=2
  STEP_A_D(0xB1, !(b2 ^ b1));
  // k=4
  STEP_A_D(0x4E, !(b4 ^ b2)); STEP_A_D(0xB1, !(b4 ^ b1));
  // k=8
  STEP_A_S(4, !(b8 ^ b4)); STEP_A_D(0x4E, !(b8 ^ b2)); STEP_A_D(0xB1, !(b8 ^ b1));
  // k=16
  STEP_A_S(8, !(b16 ^ b8)); STEP_A_S(4, !(b16 ^ b4));
  STEP_A_D(0x4E, !(b16 ^ b2)); STEP_A_D(0xB1, !(b16 ^ b1));
  // k=32
  STEP_A_S(16, !(b32 ^ b16)); STEP_A_S(8, !(b32 ^ b8)); STEP_A_S(4, !(b32 ^ b4));
  STEP_A_D(0x4E, !(b32 ^ b2)); STEP_A_D(0xB1, !(b32 ^ b1));
  // k=64 (lane&64 == 0 always)
  STEP_A_W(!b32);
  STEP_A_S(16, !b16); STEP_A_S(8, !b8); STEP_A_S(4, !b4);
  STEP_A_D(0x4E, !b2); STEP_A_D(0xB1, !b1);

  u64 av = k0 >= k1 ? k0 : k1;  // bitonic; holds the top-64 set
  STEP_B_W(!b32);
  STEP_B_S(16, !b16); STEP_B_S(8, !b8); STEP_B_S(4, !b4);
  STEP_B_D(0x4E, !b2); STEP_B_D(0xB1, !b1);

  // ---- softmax over first kk entries; lane = rank (sorted desc)
  float val = __uint_as_float((unsigned)(av >> 32));
  unsigned midx = 2047u - (unsigned)(av & 0xffffffffull);
  bool valid = (int)lane < kk;

  float vmx = __uint_as_float(
      (unsigned)__builtin_amdgcn_readfirstlane((int)(unsigned)(av >> 32)));
  float e = valid ? __expf(val - vmx) : 0.0f;
  float s = e;
  SCAN_ADD_F(s);
  float stot = __uint_as_float(RDL(__float_as_uint(s), 63));
  float w = valid ? (e / stot) : 0.0f;

  size_t o = (size_t)row * KOUT + lane;
  out_w[o] = w;
  out_i[o] = valid ? (float)midx : 0.0f;
}

extern "C" void kernel_launch(void* const* d_in, const int* in_sizes, int n_in,
                              void* d_out, int out_size, void* d_ws, size_t ws_size,
                              hipStream_t stream) {
  const float* A = (const float*)d_in[0];
  const int* topk = (const int*)d_in[1];
  float* out = (float*)d_out;
  const int NQ = in_sizes[0] / M_COLS;
  const int N = in_sizes[1] > 0 ? in_sizes[1] : 1;
  const int Q = NQ / N;
  float* out_w = out;
  float* out_i = out + (size_t)NQ * KOUT;
  const int blocks = (NQ + 3) / 4;
  hipLaunchKernelGGL(topk_route_kernel, dim3(blocks), dim3(BLK), 0, stream, A,
                     topk, out_w, out_i, NQ, Q, N);
}